// Round 9
// baseline (580.653 us; speedup 1.0000x reference)
//
#include <hip/hip_runtime.h>
#include <hip/hip_cooperative_groups.h>

namespace cg = cooperative_groups;

// Problem constants (match reference)
#define N_PTS   1000000
#define C_DIM   128
#define B_DIM   8
#define Y_DIM   468
#define X_DIM   468
#define YX      (Y_DIM * X_DIM)         // 219024
#define KSPACE  (B_DIM * YX)            // 1752192 dense key space

// Scan config
#define WG   256
#define EPT  8
#define EPB  (WG * EPT)                 // 2048 elements per scan block
#define NBLK ((KSPACE + EPB - 1) / EPB) // 856

// 3-field packed scan element: [0:21) point-count, [21:42) unique-count, [42:63) multi-count
#define F_BITS 21
#define F_MASK 0x1FFFFFu
#define SINGLE_FLAG (1ull << 63)

#define PAD_BLOCKS 2048

// native vector type for nontemporal builtins (HIP's float4 is a class)
typedef float f4 __attribute__((ext_vector_type(4)));

__device__ __forceinline__ unsigned long long shfl_up_u64(unsigned long long v, int delta) {
    unsigned lo = (unsigned)v;
    unsigned hi = (unsigned)(v >> 32);
    lo = __shfl_up(lo, delta, 64);
    hi = __shfl_up(hi, delta, 64);
    return ((unsigned long long)hi << 32) | lo;
}

// ---------------------------------------------------------------- fused meta kernel (cooperative):
// phase 0: histogram + key cache        (grid-stride over points)
// phase 1: per-block scan of packed (count|unique|multi) -> pairs, bsums
// phase 2: block 0 scans bsums (exclusive) + grand total
// phase 3: uniq — outI for every unique key (rank-sequential) + multi worklist
__global__ void __launch_bounds__(WG)
meta_kernel(const int* __restrict__ idx, unsigned* __restrict__ cnt,
            unsigned* __restrict__ keys, unsigned long long* __restrict__ pairs,
            unsigned long long* __restrict__ bsums, uint4* __restrict__ wl,
            float* __restrict__ outI, int n, int K) {
    cg::grid_group grid = cg::this_grid();
    const int tid  = threadIdx.x;
    const int lane = tid & 63;
    const int wid  = tid >> 6;
    __shared__ unsigned long long wsum[WG / 64];

    // ---- phase 0: histogram ----
    {
        int stride = NBLK * WG;
        for (int i = blockIdx.x * WG + tid; i < n; i += stride) {
            int4 v = ((const int4*)idx)[i];      // (b, z, y, x)
            unsigned key = (unsigned)(v.x * YX + v.z * X_DIM + v.w);
            keys[i] = key;
            atomicAdd(&cnt[key], 1u);
        }
    }
    grid.sync();

    // ---- phase 1: per-block exclusive scan ----
    int base = blockIdx.x * EPB + tid * EPT;
    unsigned long long p[EPT];
    unsigned cc[EPT];
    unsigned long long run = 0;
#pragma unroll
    for (int j = 0; j < EPT; ++j) {
        int k = base + j;
        unsigned c = (k < K) ? cnt[k] : 0u;
        cc[j] = c;
        unsigned long long pr = (unsigned long long)c
                              | ((unsigned long long)(c ? 1u : 0u) << F_BITS)
                              | ((unsigned long long)(c >= 2u ? 1u : 0u) << (2 * F_BITS));
        p[j] = run;                           // exclusive within thread
        run += pr;
    }
    unsigned long long tot = run;
    unsigned long long v = tot;
#pragma unroll
    for (int d = 1; d < 64; d <<= 1) {
        unsigned long long nv = shfl_up_u64(v, d);
        if (lane >= d) v += nv;
    }
    if (lane == 63) wsum[wid] = v;
    __syncthreads();
    unsigned long long wexcl = 0;
    for (int w = 0; w < wid; ++w) wexcl += wsum[w];
    unsigned long long texcl = wexcl + v - tot;   // exclusive across threads in block
#pragma unroll
    for (int j = 0; j < EPT; ++j) {
        int k = base + j;
        if (k < K)
            pairs[k] = (texcl + p[j]) | (cc[j] == 1u ? SINGLE_FLAG : 0ull);
    }
    if (tid == WG - 1) bsums[blockIdx.x] = wexcl + v;  // block total
    grid.sync();

    // ---- phase 2: block 0 exclusive-scans the 856 block sums ----
    if (blockIdx.x == 0) {
        const int SEG = 4;                     // 256 threads x 4 = 1024 >= NBLK
        unsigned long long loc[SEG];
        unsigned long long run2 = 0;
#pragma unroll
        for (int j = 0; j < SEG; ++j) {
            int i = tid * SEG + j;
            loc[j] = run2;
            run2 += (i < NBLK) ? bsums[i] : 0ull;
        }
        unsigned long long tot2 = run2;
        unsigned long long v2 = tot2;
#pragma unroll
        for (int d = 1; d < 64; d <<= 1) {
            unsigned long long nv = shfl_up_u64(v2, d);
            if (lane >= d) v2 += nv;
        }
        __syncthreads();                       // reuse wsum
        if (lane == 63) wsum[wid] = v2;
        __syncthreads();
        unsigned long long wexcl2 = 0;
        for (int w = 0; w < wid; ++w) wexcl2 += wsum[w];
        unsigned long long texcl2 = wexcl2 + v2 - tot2;
#pragma unroll
        for (int j = 0; j < SEG; ++j) {
            int i = tid * SEG + j;
            if (i < NBLK) bsums[i] = texcl2 + loc[j];
        }
        if (tid == WG - 1) bsums[NBLK] = wexcl2 + v2;  // grand total
    }
    grid.sync();

    // ---- phase 3: uniq (register-resident cc/p/texcl) ----
    unsigned long long bofs = bsums[blockIdx.x];
#pragma unroll
    for (int j = 0; j < EPT; ++j) {
        int k = base + j;
        if (k >= K) break;
        unsigned c = cc[j];
        if (c == 0) continue;
        unsigned long long pr = texcl + p[j] + bofs;
        unsigned rank = (unsigned)((pr >> F_BITS) & F_MASK);
        unsigned bb  = (unsigned)k / YX;
        unsigned rem = (unsigned)k % YX;
        outI[(size_t)rank * 3 + 0] = (float)bb;
        outI[(size_t)rank * 3 + 1] = (float)(rem / X_DIM);
        outI[(size_t)rank * 3 + 2] = (float)(rem % X_DIM);
        if (c >= 2) {
            unsigned start = (unsigned)(pr & F_MASK);
            unsigned mslot = (unsigned)((pr >> (2 * F_BITS)) & F_MASK);
            wl[mslot] = make_uint4(start, start + c, (unsigned)k, rank);
        }
    }
}

// ---------------------------------------------------------------- fused per-point pass + pad fill
// Point blocks: 8 points per wave (8 lanes/point, 4 float4 slots per lane).
// Pad blocks (appended to grid): stream zero rows [nU, n).
__global__ void __launch_bounds__(256)
pointscatter_pad_kernel(const float* __restrict__ feat, const unsigned* __restrict__ keys,
                        const unsigned long long* __restrict__ pairs,
                        const unsigned long long* __restrict__ bsums,
                        unsigned* __restrict__ cnt, unsigned* __restrict__ pids,
                        float* __restrict__ outF, float* __restrict__ outI,
                        const unsigned long long* __restrict__ total,
                        int n, int pointBlocks) {
    int lane = threadIdx.x & 63;
    int wid  = threadIdx.x >> 6;
    int e    = lane >> 3;                 // point / row within wave's 8
    int sub  = lane & 7;                  // float4 slots sub, sub+8, sub+16, sub+24
    if ((int)blockIdx.x < pointBlocks) {
        long p = (long)blockIdx.x * 32 + wid * 8 + e;
        if (p >= n) return;
        unsigned key = keys[p];
        unsigned long long pr = pairs[key];
        if (pr >> 63) {                   // singleton: copy own row to out[rank]
            pr += bsums[key >> 11];
            unsigned rank = (unsigned)((pr >> F_BITS) & F_MASK);
            const f4* src = (const f4*)(feat + (size_t)p * C_DIM);
            f4*       dst = (f4*)(outF + (size_t)rank * C_DIM);
            f4 v0 = __builtin_nontemporal_load(src + sub);
            f4 v1 = __builtin_nontemporal_load(src + sub + 8);
            f4 v2 = __builtin_nontemporal_load(src + sub + 16);
            f4 v3 = __builtin_nontemporal_load(src + sub + 24);
            __builtin_nontemporal_store(v0, dst + sub);
            __builtin_nontemporal_store(v1, dst + sub + 8);
            __builtin_nontemporal_store(v2, dst + sub + 16);
            __builtin_nontemporal_store(v3, dst + sub + 24);
        } else if (sub == 0) {            // multi: scatter pid (cnt doubles as cursor)
            unsigned start = (unsigned)((pr + bsums[key >> 11]) & F_MASK);
            unsigned off = atomicSub(&cnt[key], 1u) - 1u;    // c-1, ..., 0
            pids[start + off] = (unsigned)p;
        }
    } else {
        // pad rows [nU, n): zeros + (-1, 467, 467)
        unsigned long long tot = *total;
        long nU = (long)((tot >> F_BITS) & F_MASK);
        long base   = nU + (long)((int)blockIdx.x - pointBlocks) * 32 + wid * 8 + e;
        long stride = (long)(gridDim.x - pointBlocks) * 32;
        f4 z = (f4)(0.f);
        for (long r = base; r < n; r += stride) {
            f4* dst = (f4*)(outF + (size_t)r * C_DIM);
            __builtin_nontemporal_store(z, dst + sub);
            __builtin_nontemporal_store(z, dst + sub + 8);
            __builtin_nontemporal_store(z, dst + sub + 16);
            __builtin_nontemporal_store(z, dst + sub + 24);
            if (sub == 0) {
                outI[(size_t)r * 3 + 0] = -1.0f;
                outI[(size_t)r * 3 + 1] = 467.0f;   // (-1 % YX) // X per numpy floor-mod
                outI[(size_t)r * 3 + 2] = 467.0f;
            }
        }
    }
}

// ---------------------------------------------------------------- multi gather+sum: 4 rows/wave, paired-pid unroll
__global__ void __launch_bounds__(256)
multi_kernel(const float* __restrict__ feat, const unsigned* __restrict__ pointIds,
             const uint4* __restrict__ wl,
             const unsigned long long* __restrict__ total,
             float* __restrict__ outF) {
    int lane = threadIdx.x & 63;
    int wid  = threadIdx.x >> 6;
    int rq   = lane >> 4;                 // row within wave's 4
    int sub  = lane & 15;                 // float4 slots sub, sub+16
    long m = (long)(((*total) >> (2 * F_BITS)) & F_MASK);
    long base   = (long)blockIdx.x * 16 + wid * 4 + rq;
    long stride = (long)gridDim.x * 16;
    for (long r = base; r < m; r += stride) {
        uint4 d = wl[r];
        f4 a0 = (f4)(0.f);
        f4 a1 = (f4)(0.f);
        unsigned j = d.x, e = d.y;
        for (; j + 1 < e; j += 2) {       // paired: 4 independent row-half loads in flight
            unsigned p0 = pointIds[j];
            unsigned p1 = pointIds[j + 1];
            const f4* s0 = (const f4*)(feat + (size_t)p0 * C_DIM);
            const f4* s1 = (const f4*)(feat + (size_t)p1 * C_DIM);
            f4 v00 = __builtin_nontemporal_load(s0 + sub);
            f4 v01 = __builtin_nontemporal_load(s0 + sub + 16);
            f4 v10 = __builtin_nontemporal_load(s1 + sub);
            f4 v11 = __builtin_nontemporal_load(s1 + sub + 16);
            a0 += v00 + v10;
            a1 += v01 + v11;
        }
        if (j < e) {
            unsigned p0 = pointIds[j];
            const f4* s0 = (const f4*)(feat + (size_t)p0 * C_DIM);
            f4 v00 = __builtin_nontemporal_load(s0 + sub);
            f4 v01 = __builtin_nontemporal_load(s0 + sub + 16);
            a0 += v00;
            a1 += v01;
        }
        f4* dst = (f4*)(outF + (size_t)d.w * C_DIM);
        __builtin_nontemporal_store(a0, dst + sub);
        __builtin_nontemporal_store(a1, dst + sub + 16);
    }
}

extern "C" void kernel_launch(void* const* d_in, const int* in_sizes, int n_in,
                              void* d_out, int out_size, void* d_ws, size_t ws_size,
                              hipStream_t stream) {
    const float* feat = (const float*)d_in[0];
    const int*   idx  = (const int*)d_in[1];
    const int n = in_sizes[0] / C_DIM;   // 1,000,000
    const int K = KSPACE;

    // workspace layout (256B aligned slices)
    char* ws = (char*)d_ws;
    size_t off = 0;
    auto take = [&](size_t bytes) {
        size_t cur = off;
        off = (off + bytes + 255) & ~(size_t)255;
        return cur;
    };
    size_t o_cnt    = take((size_t)K * 4);        // count per key (later reused as scatter cursor)
    size_t o_keys   = take((size_t)n * 4);        // cached keys per point
    size_t o_pairs  = take((size_t)K * 8);        // packed scan prefixes + singleton flag
    size_t o_bsums  = take((size_t)(NBLK + 1) * 8);
    size_t o_pids   = take((size_t)n * 4);        // point ids (multi buckets only)
    size_t o_wl     = take((size_t)(n / 2 + 1) * 16);  // worklist {start,end,key,rank}

    unsigned*           cnt    = (unsigned*)(ws + o_cnt);
    unsigned*           keys   = (unsigned*)(ws + o_keys);
    unsigned long long* pairs  = (unsigned long long*)(ws + o_pairs);
    unsigned long long* bsums  = (unsigned long long*)(ws + o_bsums);
    unsigned*           pids   = (unsigned*)(ws + o_pids);
    uint4*              wl     = (uint4*)(ws + o_wl);

    float* outF = (float*)d_out;
    float* outI = outF + (size_t)n * C_DIM;

    // 1. zero cnt (fill-rate, no kernel launch)
    hipMemsetAsync(cnt, 0, (size_t)K * 4, stream);

    // 2. fused meta: hist -> scan -> scan2 -> uniq (one cooperative launch)
    {
        int nArg = n, KArg = K;
        void* args[] = { (void*)&idx, (void*)&cnt, (void*)&keys, (void*)&pairs,
                         (void*)&bsums, (void*)&wl, (void*)&outI, (void*)&nArg, (void*)&KArg };
        hipLaunchCooperativeKernel((const void*)meta_kernel, dim3(NBLK), dim3(WG),
                                   args, 0, stream);
    }

    // 3. fused per-point pass (singleton copy / pid scatter) + pad fill
    {
        int pointBlocks = (n + 31) / 32;
        pointscatter_pad_kernel<<<pointBlocks + PAD_BLOCKS, 256, 0, stream>>>(
            feat, keys, pairs, bsums, cnt, pids, outF, outI, bsums + NBLK, n, pointBlocks);
    }
    // 4. multi gather+sum
    multi_kernel<<<4096, 256, 0, stream>>>(feat, pids, wl, bsums + NBLK, outF);
}

// Round 10
// 280.365 us; speedup vs baseline: 2.0711x; 2.0711x over previous
//
#include <hip/hip_runtime.h>

// Problem constants (match reference)
#define N_PTS   1000000
#define C_DIM   128
#define B_DIM   8
#define Y_DIM   468
#define X_DIM   468
#define YX      (Y_DIM * X_DIM)         // 219024
#define KSPACE  (B_DIM * YX)            // 1752192 dense key space

// Scan config
#define WG   256
#define EPT  8
#define EPB  (WG * EPT)                 // 2048 elements per scan block
#define NBLK ((KSPACE + EPB - 1) / EPB) // 856

// 3-field packed scan element: [0:21) point-count, [21:42) unique-count, [42:63) multi-count
#define F_BITS 21
#define F_MASK 0x1FFFFFu
#define SINGLE_FLAG (1ull << 63)

#define PAD_BLOCKS 2048

// native vector type for nontemporal builtins (HIP's float4 is a class)
typedef float f4 __attribute__((ext_vector_type(4)));

__device__ __forceinline__ unsigned long long shfl_up_u64(unsigned long long v, int delta) {
    unsigned lo = (unsigned)v;
    unsigned hi = (unsigned)(v >> 32);
    lo = __shfl_up(lo, delta, 64);
    hi = __shfl_up(hi, delta, 64);
    return ((unsigned long long)hi << 32) | lo;
}

// ---------------------------------------------------------------- histogram + key cache
__global__ void hist_kernel(const int* __restrict__ idx, unsigned* __restrict__ cnt,
                            unsigned* __restrict__ keys, int n) {
    int i = blockIdx.x * blockDim.x + threadIdx.x;
    if (i >= n) return;
    int4 v = ((const int4*)idx)[i];          // (b, z, y, x)
    unsigned key = (unsigned)(v.x * YX + v.z * X_DIM + v.w);
    keys[i] = key;
    atomicAdd(&cnt[key], 1u);
}

// ---------------------------------------------------------------- scan pass 1: per-block exclusive scan of packed (count|unique|multi)
// pairs[k] = exclusive prefix within block, bit63 = (cnt[k]==1)
__global__ void scan1_kernel(const unsigned* __restrict__ cnt,
                             unsigned long long* __restrict__ pairs,
                             unsigned long long* __restrict__ bsums, int K) {
    int base = blockIdx.x * EPB + threadIdx.x * EPT;
    unsigned long long p[EPT];
    unsigned cc[EPT];
    unsigned long long run = 0;
#pragma unroll
    for (int j = 0; j < EPT; ++j) {
        int k = base + j;
        unsigned c = (k < K) ? cnt[k] : 0u;
        cc[j] = c;
        unsigned long long pr = (unsigned long long)c
                              | ((unsigned long long)(c ? 1u : 0u) << F_BITS)
                              | ((unsigned long long)(c >= 2u ? 1u : 0u) << (2 * F_BITS));
        p[j] = run;                           // exclusive within thread
        run += pr;
    }
    unsigned long long tot = run;
    // inclusive wave scan of thread totals
    int lane = threadIdx.x & 63;
    unsigned long long v = tot;
#pragma unroll
    for (int d = 1; d < 64; d <<= 1) {
        unsigned long long nv = shfl_up_u64(v, d);
        if (lane >= d) v += nv;
    }
    __shared__ unsigned long long wsum[WG / 64];
    int wid = threadIdx.x >> 6;
    if (lane == 63) wsum[wid] = v;
    __syncthreads();
    unsigned long long wexcl = 0;
    for (int w = 0; w < wid; ++w) wexcl += wsum[w];
    unsigned long long texcl = wexcl + v - tot;   // exclusive across threads in block
#pragma unroll
    for (int j = 0; j < EPT; ++j) {
        int k = base + j;
        if (k < K)
            pairs[k] = (texcl + p[j]) | (cc[j] == 1u ? SINGLE_FLAG : 0ull);
    }
    if (threadIdx.x == WG - 1) bsums[blockIdx.x] = wexcl + v;  // block total
}

// ---------------------------------------------------------------- scan pass 2: exclusive scan of block sums (single block, nb <= 1024)
__global__ void scan2_kernel(unsigned long long* __restrict__ bsums, int nb) {
    int t = threadIdx.x;
    unsigned long long orig = (t < nb) ? bsums[t] : 0ull;
    unsigned long long v = orig;
    int lane = t & 63;
#pragma unroll
    for (int d = 1; d < 64; d <<= 1) {
        unsigned long long nv = shfl_up_u64(v, d);
        if (lane >= d) v += nv;
    }
    __shared__ unsigned long long ws[1024 / 64];
    int wid = t >> 6;
    if (lane == 63) ws[wid] = v;
    __syncthreads();
    unsigned long long wexcl = 0;
    for (int w = 0; w < wid; ++w) wexcl += ws[w];
    if (t < nb) bsums[t] = wexcl + v - orig;      // exclusive
    if (t == 1023) {                              // grand total -> bsums[nb]
        unsigned long long tt = 0;
        for (int w = 0; w < 1024 / 64; ++w) tt += ws[w];
        bsums[nb] = tt;
    }
}

// ---------------------------------------------------------------- heavy fused kernel: [uniq | point | pad] block ranges
// uniq blocks: per-key counts derived from ADJACENT scan prefixes (no cnt
//   read -> no race with point blocks' atomicSub cursor). Sequential outI
//   writes + multi worklist.
// point blocks: 8 points/wave; singleton row copy OR pid scatter.
// pad blocks: stream zero rows [nU, n).
__global__ void __launch_bounds__(256)
heavy_kernel(const float* __restrict__ feat, const unsigned* __restrict__ keys,
             const unsigned long long* __restrict__ pairs,
             const unsigned long long* __restrict__ bsums,
             unsigned* __restrict__ cnt, unsigned* __restrict__ pids,
             uint4* __restrict__ wl,
             float* __restrict__ outF, float* __restrict__ outI,
             int n, int K, int pointBlocks) {
    int tid  = threadIdx.x;
    int lane = tid & 63;
    int wid  = tid >> 6;
    int bid  = blockIdx.x;

    if (bid < NBLK) {
        // ---- uniq range ----
        int base = bid * EPB + tid * EPT;
        if (base >= K) return;
        unsigned long long bofs = bsums[bid];     // same scan-block for keys base..base+7
        unsigned long long P[EPT + 1];
#pragma unroll
        for (int j = 0; j < EPT; ++j) {
            int k = base + j;
            P[j] = (k < K) ? ((pairs[k] & ~SINGLE_FLAG) + bofs) : bsums[NBLK];
        }
        {
            int k = base + EPT;                   // neighbor (crosses scan-block only at tid==255)
            P[EPT] = (k < K) ? ((pairs[k] & ~SINGLE_FLAG) + bsums[k >> 11]) : bsums[NBLK];
        }
#pragma unroll
        for (int j = 0; j < EPT; ++j) {
            int k = base + j;
            if (k >= K) break;
            unsigned long long diff = P[j + 1] - P[j];   // monotonic fields: no borrow
            unsigned c = (unsigned)(diff & F_MASK);
            if (c == 0) continue;
            unsigned rank = (unsigned)((P[j] >> F_BITS) & F_MASK);
            unsigned bb  = (unsigned)k / YX;
            unsigned rem = (unsigned)k % YX;
            outI[(size_t)rank * 3 + 0] = (float)bb;
            outI[(size_t)rank * 3 + 1] = (float)(rem / X_DIM);
            outI[(size_t)rank * 3 + 2] = (float)(rem % X_DIM);
            if (c >= 2) {
                unsigned start = (unsigned)(P[j] & F_MASK);
                unsigned mslot = (unsigned)((P[j] >> (2 * F_BITS)) & F_MASK);
                wl[mslot] = make_uint4(start, start + c, (unsigned)k, rank);
            }
        }
    } else if (bid < NBLK + pointBlocks) {
        // ---- point range: 8 points per wave (8 lanes/point, 4 f4 slots each) ----
        int e   = lane >> 3;
        int sub = lane & 7;
        long p = (long)(bid - NBLK) * 32 + wid * 8 + e;
        if (p >= n) return;
        unsigned key = keys[p];
        unsigned long long pr = pairs[key];
        if (pr >> 63) {                   // singleton: copy own row to out[rank]
            pr += bsums[key >> 11];
            unsigned rank = (unsigned)((pr >> F_BITS) & F_MASK);
            const f4* src = (const f4*)(feat + (size_t)p * C_DIM);
            f4*       dst = (f4*)(outF + (size_t)rank * C_DIM);
            f4 v0 = __builtin_nontemporal_load(src + sub);
            f4 v1 = __builtin_nontemporal_load(src + sub + 8);
            f4 v2 = __builtin_nontemporal_load(src + sub + 16);
            f4 v3 = __builtin_nontemporal_load(src + sub + 24);
            __builtin_nontemporal_store(v0, dst + sub);
            __builtin_nontemporal_store(v1, dst + sub + 8);
            __builtin_nontemporal_store(v2, dst + sub + 16);
            __builtin_nontemporal_store(v3, dst + sub + 24);
        } else if (sub == 0) {            // multi: scatter pid (cnt doubles as cursor)
            unsigned start = (unsigned)((pr + bsums[key >> 11]) & F_MASK);
            unsigned off = atomicSub(&cnt[key], 1u) - 1u;    // c-1, ..., 0
            pids[start + off] = (unsigned)p;
        }
    } else {
        // ---- pad range: rows [nU, n) -> zeros + (-1, 467, 467) ----
        int e   = lane >> 3;
        int sub = lane & 7;
        unsigned long long tot = bsums[NBLK];
        long nU = (long)((tot >> F_BITS) & F_MASK);
        long pb = bid - NBLK - pointBlocks;
        long base   = nU + pb * 32 + wid * 8 + e;
        long stride = (long)PAD_BLOCKS * 32;
        f4 z = (f4)(0.f);
        for (long r = base; r < n; r += stride) {
            f4* dst = (f4*)(outF + (size_t)r * C_DIM);
            __builtin_nontemporal_store(z, dst + sub);
            __builtin_nontemporal_store(z, dst + sub + 8);
            __builtin_nontemporal_store(z, dst + sub + 16);
            __builtin_nontemporal_store(z, dst + sub + 24);
            if (sub == 0) {
                outI[(size_t)r * 3 + 0] = -1.0f;
                outI[(size_t)r * 3 + 1] = 467.0f;   // (-1 % YX) // X per numpy floor-mod
                outI[(size_t)r * 3 + 2] = 467.0f;
            }
        }
    }
}

// ---------------------------------------------------------------- multi gather+sum: 4 rows/wave, paired-pid unroll
__global__ void __launch_bounds__(256)
multi_kernel(const float* __restrict__ feat, const unsigned* __restrict__ pointIds,
             const uint4* __restrict__ wl,
             const unsigned long long* __restrict__ total,
             float* __restrict__ outF) {
    int lane = threadIdx.x & 63;
    int wid  = threadIdx.x >> 6;
    int rq   = lane >> 4;                 // row within wave's 4
    int sub  = lane & 15;                 // float4 slots sub, sub+16
    long m = (long)(((*total) >> (2 * F_BITS)) & F_MASK);
    long base   = (long)blockIdx.x * 16 + wid * 4 + rq;
    long stride = (long)gridDim.x * 16;
    for (long r = base; r < m; r += stride) {
        uint4 d = wl[r];
        f4 a0 = (f4)(0.f);
        f4 a1 = (f4)(0.f);
        unsigned j = d.x, e = d.y;
        for (; j + 1 < e; j += 2) {       // paired: 4 independent row-half loads in flight
            unsigned p0 = pointIds[j];
            unsigned p1 = pointIds[j + 1];
            const f4* s0 = (const f4*)(feat + (size_t)p0 * C_DIM);
            const f4* s1 = (const f4*)(feat + (size_t)p1 * C_DIM);
            f4 v00 = __builtin_nontemporal_load(s0 + sub);
            f4 v01 = __builtin_nontemporal_load(s0 + sub + 16);
            f4 v10 = __builtin_nontemporal_load(s1 + sub);
            f4 v11 = __builtin_nontemporal_load(s1 + sub + 16);
            a0 += v00 + v10;
            a1 += v01 + v11;
        }
        if (j < e) {
            unsigned p0 = pointIds[j];
            const f4* s0 = (const f4*)(feat + (size_t)p0 * C_DIM);
            f4 v00 = __builtin_nontemporal_load(s0 + sub);
            f4 v01 = __builtin_nontemporal_load(s0 + sub + 16);
            a0 += v00;
            a1 += v01;
        }
        f4* dst = (f4*)(outF + (size_t)d.w * C_DIM);
        __builtin_nontemporal_store(a0, dst + sub);
        __builtin_nontemporal_store(a1, dst + sub + 16);
    }
}

extern "C" void kernel_launch(void* const* d_in, const int* in_sizes, int n_in,
                              void* d_out, int out_size, void* d_ws, size_t ws_size,
                              hipStream_t stream) {
    const float* feat = (const float*)d_in[0];
    const int*   idx  = (const int*)d_in[1];
    const int n = in_sizes[0] / C_DIM;   // 1,000,000
    const int K = KSPACE;

    // workspace layout (256B aligned slices)
    char* ws = (char*)d_ws;
    size_t off = 0;
    auto take = [&](size_t bytes) {
        size_t cur = off;
        off = (off + bytes + 255) & ~(size_t)255;
        return cur;
    };
    size_t o_cnt    = take((size_t)K * 4);        // count per key (reused as scatter cursor)
    size_t o_keys   = take((size_t)n * 4);        // cached keys per point
    size_t o_pairs  = take((size_t)K * 8);        // packed scan prefixes + singleton flag
    size_t o_bsums  = take((size_t)(NBLK + 1) * 8);
    size_t o_pids   = take((size_t)n * 4);        // point ids (multi buckets only)
    size_t o_wl     = take((size_t)(n / 2 + 1) * 16);  // worklist {start,end,key,rank}

    unsigned*           cnt    = (unsigned*)(ws + o_cnt);
    unsigned*           keys   = (unsigned*)(ws + o_keys);
    unsigned long long* pairs  = (unsigned long long*)(ws + o_pairs);
    unsigned long long* bsums  = (unsigned long long*)(ws + o_bsums);
    unsigned*           pids   = (unsigned*)(ws + o_pids);
    uint4*              wl     = (uint4*)(ws + o_wl);

    float* outF = (float*)d_out;
    float* outI = outF + (size_t)n * C_DIM;

    // 1. zero cnt (fill-rate)
    hipMemsetAsync(cnt, 0, (size_t)K * 4, stream);
    // 2. histogram + cache keys
    hist_kernel<<<(n + 255) / 256, 256, 0, stream>>>(idx, cnt, keys, n);
    // 3-4. two-level exclusive scan of packed (count|unique|multi)
    scan1_kernel<<<NBLK, WG, 0, stream>>>(cnt, pairs, bsums, K);
    scan2_kernel<<<1, 1024, 0, stream>>>(bsums, NBLK);
    // 5. fused heavy pass: [uniq | point copy/scatter | pad]
    {
        int pointBlocks = (n + 31) / 32;
        heavy_kernel<<<NBLK + pointBlocks + PAD_BLOCKS, 256, 0, stream>>>(
            feat, keys, pairs, bsums, cnt, pids, wl, outF, outI, n, K, pointBlocks);
    }
    // 6. multi gather+sum
    multi_kernel<<<4096, 256, 0, stream>>>(feat, pids, wl, bsums + NBLK, outF);
}